// Round 6
// baseline (157.176 us; speedup 1.0000x reference)
//
#include <hip/hip_runtime.h>
#include <hip/hip_bf16.h>

// EfficientMultiScaleROIExtractor for MI355X (gfx950)
// fm: [1,64,120,120] f32, boxes: [4096,4] f32, MLP weights f32.
//
// K1 k_transpose_mean: CHW->HWC + per-block channel partial sums
// K2 k_ghead: global mean -> shared head -> folded f1 bias (f1pre[128])
// K3 k_fused: 1 wave = 1 box, no barriers, no cross-wave LDS.
//   phase A (pool): lane = (pg=point-group 0..3, qc=channel-quad 0..15).
//     Each 16-lane group recomputes its grid point's address/weights
//     INLINE (redundant lockstep VALU — free, we're latency-bound) and
//     fetches one corner for 4 points at once (16 lanes x float4 = 64 ch
//     = 1KB coalesced). No offset/weight tables -> LDS 14.3KB/block ->
//     8 blocks/CU = 8 waves/SIMD for latency hiding.
//   phase B (MLP): activations broadcast via uniform-address ds_read_b128
//     from per-wave LDS; weights 256B-coalesced, identical across waves.

#define HW 120
#define NPIX (HW * HW)   // 14400

__global__ __launch_bounds__(256) void k_transpose_mean(
    const float* __restrict__ fm, float* __restrict__ fm_t,
    float* __restrict__ partial)
{
    __shared__ float tile[64][65];
    __shared__ float pr[4][64];
    const int t  = threadIdx.x;
    const int tx = t & 63;
    const int ty = t >> 6;
    const int pix0 = blockIdx.x * 64;   // 225 blocks * 64 pixels = 14400

    #pragma unroll
    for (int k = 0; k < 16; ++k) {
        const int c = k * 4 + ty;
        tile[c][tx] = fm[c * NPIX + pix0 + tx];   // coalesced read
    }
    __syncthreads();
    #pragma unroll
    for (int k = 0; k < 16; ++k) {
        const int p = k * 4 + ty;
        fm_t[(pix0 + p) * 64 + tx] = tile[tx][p]; // coalesced write
    }
    float s = 0.f;
    #pragma unroll
    for (int k = 0; k < 16; ++k) s += tile[tx][ty * 16 + k];
    pr[ty][tx] = s;
    __syncthreads();
    if (t < 64)
        partial[blockIdx.x * 64 + t] = pr[0][t] + pr[1][t] + pr[2][t] + pr[3][t];
}

__global__ __launch_bounds__(256) void k_ghead(
    const float* __restrict__ partial,
    const float* __restrict__ w1, const float* __restrict__ b1,
    const float* __restrict__ w2, const float* __restrict__ b2,
    const float* __restrict__ p1, const float* __restrict__ pb1,
    float* __restrict__ f1pre)
{
    __shared__ float pr[4][64];
    __shared__ float g[64];
    __shared__ float h[128];
    __shared__ float gh[64];
    const int t = threadIdx.x;
    const int c = t & 63, q = t >> 6;
    float s = 0.f;
    for (int b = q; b < 225; b += 4) s += partial[b * 64 + c];
    pr[q][c] = s;
    __syncthreads();
    if (t < 64) g[t] = (pr[0][t] + pr[1][t] + pr[2][t] + pr[3][t]) * (1.f / 14400.f);
    __syncthreads();
    if (t < 128) {
        float a = b1[t];
        #pragma unroll 8
        for (int cc = 0; cc < 64; ++cc) a = fmaf(g[cc], w1[cc * 128 + t], a);
        h[t] = fmaxf(a, 0.f);
    }
    __syncthreads();
    if (t < 64) {
        float a = b2[t];
        #pragma unroll 8
        for (int k = 0; k < 128; ++k) a = fmaf(h[k], w2[k * 64 + t], a);
        gh[t] = fmaxf(a, 0.f);
    }
    __syncthreads();
    if (t < 128) {
        float a = pb1[t];
        #pragma unroll 8
        for (int j = 0; j < 64; ++j) a = fmaf(gh[j], p1[(192 + j) * 128 + t], a);
        f1pre[t] = a;   // no relu: relu happens after cat@p1 contribution
    }
}

// One scale's gather. Each 16-lane group walks points lp = pg, pg+4, ...
// recomputing the point's bilinear setup inline (lockstep within group).
template <int R>
__device__ __forceinline__ float4 gather_seg(
    const char* __restrict__ fb, int pg,
    float cx, float cy, float bw2, float bh2)
{
    constexpr float invR = 1.f / (float)R;
    constexpr float s2   = invR * invR;          // folds the mean
    float ax = 0.f, ay = 0.f, az = 0.f, aw = 0.f;
    #pragma unroll 2
    for (int lp = pg; lp < R * R; lp += 4) {
        const int i = lp / R;                    // constexpr R -> magic mul
        const int j = lp - i * R;
        const float liny = (float)(2 * i + 1) * invR - 1.f;
        const float linx = (float)(2 * j + 1) * invR - 1.f;
        const float gy = cy + bh2 * liny;
        const float gx = cx + bw2 * linx;
        const float iy = ((gy + 1.f) * 120.f - 1.f) * 0.5f;
        const float ix = ((gx + 1.f) * 120.f - 1.f) * 0.5f;
        const float y0f = floorf(iy), x0f = floorf(ix);
        const float wy = iy - y0f,  wx = ix - x0f;
        const int y0 = (int)y0f, x0 = (int)x0f;
        const float vy0 = (y0 >= 0 && y0 < HW)      ? 1.f : 0.f;
        const float vy1 = (y0 >= -1 && y0 < HW - 1) ? 1.f : 0.f;
        const float vx0 = (x0 >= 0 && x0 < HW)      ? 1.f : 0.f;
        const float vx1 = (x0 >= -1 && x0 < HW - 1) ? 1.f : 0.f;
        const int x0c = min(max(x0, 0), HW - 1);
        const int x1c = min(max(x0 + 1, 0), HW - 1);
        const int y0c = min(max(y0, 0), HW - 1);
        const int y1c = min(max(y0 + 1, 0), HW - 1);
        const int o00 = (y0c * HW + x0c) * 256;  // one HWC pixel = 256B
        const int o01 = (y0c * HW + x1c) * 256;
        const int o10 = (y1c * HW + x0c) * 256;
        const int o11 = (y1c * HW + x1c) * 256;
        const float w00 = (1.f - wx) * (1.f - wy) * s2 * (vy0 * vx0);
        const float w01 = wx * (1.f - wy) * s2 * (vy0 * vx1);
        const float w10 = (1.f - wx) * wy * s2 * (vy1 * vx0);
        const float w11 = wx * wy * s2 * (vy1 * vx1);
        const float4 v0 = *(const float4*)(fb + o00);
        const float4 v1 = *(const float4*)(fb + o01);
        const float4 v2 = *(const float4*)(fb + o10);
        const float4 v3 = *(const float4*)(fb + o11);
        ax = fmaf(w00, v0.x, ax); ay = fmaf(w00, v0.y, ay);
        az = fmaf(w00, v0.z, az); aw = fmaf(w00, v0.w, aw);
        ax = fmaf(w01, v1.x, ax); ay = fmaf(w01, v1.y, ay);
        az = fmaf(w01, v1.z, az); aw = fmaf(w01, v1.w, aw);
        ax = fmaf(w10, v2.x, ax); ay = fmaf(w10, v2.y, ay);
        az = fmaf(w10, v2.z, az); aw = fmaf(w10, v2.w, aw);
        ax = fmaf(w11, v3.x, ax); ay = fmaf(w11, v3.y, ay);
        az = fmaf(w11, v3.z, az); aw = fmaf(w11, v3.w, aw);
    }
    // combine the 4 point-groups (lanes l, l^16, l^32, l^48)
    ax += __shfl_xor(ax, 16, 64); ay += __shfl_xor(ay, 16, 64);
    az += __shfl_xor(az, 16, 64); aw += __shfl_xor(aw, 16, 64);
    ax += __shfl_xor(ax, 32, 64); ay += __shfl_xor(ay, 32, 64);
    az += __shfl_xor(az, 32, 64); aw += __shfl_xor(aw, 32, 64);
    return make_float4(ax, ay, az, aw);
}

__global__ __launch_bounds__(256, 8) void k_fused(
    const float* __restrict__ fm_t, const float* __restrict__ boxes,
    const float* __restrict__ w1, const float* __restrict__ b1,
    const float* __restrict__ w2, const float* __restrict__ b2,
    const float* __restrict__ p1, const float* __restrict__ f1pre,
    const float* __restrict__ p2, const float* __restrict__ pb2,
    float* __restrict__ out, int N)
{
    __shared__ __align__(16) float xbufS[4][192];   // [3][64] per wave
    __shared__ __align__(16) float hbufS[4][384];   // [3][128] per wave
    __shared__ __align__(16) float cbufS[4][192];
    __shared__ __align__(16) float fbufS[4][128];

    const int t    = threadIdx.x;
    const int lane = t & 63;
    const int wid  = t >> 6;
    const int n    = blockIdx.x * 4 + wid;
    if (n >= N) return;                 // wave-uniform; no barriers anywhere

    float* xbuf = xbufS[wid];
    float* hbuf = hbufS[wid];
    float* cbuf = cbufS[wid];
    float* fbuf = fbufS[wid];

    // ---------------- phase A: 3-scale bilinear avg-pool ----------------
    const float4 bx = reinterpret_cast<const float4*>(boxes)[n];
    const float x1 = bx.x / 960.f * 2.f - 1.f;
    const float y1 = bx.y / 960.f * 2.f - 1.f;
    const float x2 = bx.z / 960.f * 2.f - 1.f;
    const float y2 = bx.w / 960.f * 2.f - 1.f;
    const float cx  = (x1 + x2) * 0.5f;
    const float cy  = (y1 + y2) * 0.5f;
    const float bw2 = fmaxf(x2 - x1, 1e-6f) * 0.5f;
    const float bh2 = fmaxf(y2 - y1, 1e-6f) * 0.5f;

    const int qc = lane & 15;           // channel quad: channels 4qc..4qc+3
    const int pg = lane >> 4;           // point group 0..3
    const char* fb = (const char*)fm_t + qc * 16;

    const float4 r0 = gather_seg<3>(fb, pg, cx, cy, bw2, bh2);
    const float4 r1 = gather_seg<7>(fb, pg, cx, cy, bw2, bh2);
    const float4 r2 = gather_seg<11>(fb, pg, cx, cy, bw2, bh2);
    if (pg == 0) {
        *(float4*)(xbuf +       4 * qc) = r0;
        *(float4*)(xbuf +  64 + 4 * qc) = r1;
        *(float4*)(xbuf + 128 + 4 * qc) = r2;
    }

    // ---------------- phase B: per-wave MLP (LDS uniform broadcasts) ----------------
    // L1: H_s = relu(X_s @ w1 + b1); lane holds outputs {lane, lane+64}
    float h0l, h0h, h1l, h1h, h2l, h2h;
    {
        const float bl = b1[lane], bh = b1[64 + lane];
        h0l = h1l = h2l = bl; h0h = h1h = h2h = bh;
        #define L1STEP(XA0, XA1, XA2, CC) {                                \
            const float wlo = w1[(CC) * 128 + lane];                       \
            const float whi = w1[(CC) * 128 + 64 + lane];                  \
            h0l = fmaf(XA0, wlo, h0l); h0h = fmaf(XA0, whi, h0h);          \
            h1l = fmaf(XA1, wlo, h1l); h1h = fmaf(XA1, whi, h1h);          \
            h2l = fmaf(XA2, wlo, h2l); h2h = fmaf(XA2, whi, h2h); }
        #pragma unroll 4
        for (int k4 = 0; k4 < 16; ++k4) {
            const float4 xv0 = *(const float4*)(xbuf +       4 * k4); // uniform -> broadcast
            const float4 xv1 = *(const float4*)(xbuf +  64 + 4 * k4);
            const float4 xv2 = *(const float4*)(xbuf + 128 + 4 * k4);
            L1STEP(xv0.x, xv1.x, xv2.x, 4 * k4 + 0)
            L1STEP(xv0.y, xv1.y, xv2.y, 4 * k4 + 1)
            L1STEP(xv0.z, xv1.z, xv2.z, 4 * k4 + 2)
            L1STEP(xv0.w, xv1.w, xv2.w, 4 * k4 + 3)
        }
        #undef L1STEP
        h0l = fmaxf(h0l, 0.f); h0h = fmaxf(h0h, 0.f);
        h1l = fmaxf(h1l, 0.f); h1h = fmaxf(h1h, 0.f);
        h2l = fmaxf(h2l, 0.f); h2h = fmaxf(h2h, 0.f);
        hbuf[lane]       = h0l; hbuf[64 + lane]  = h0h;
        hbuf[128 + lane] = h1l; hbuf[192 + lane] = h1h;
        hbuf[256 + lane] = h2l; hbuf[320 + lane] = h2h;
    }

    // L2: cat_s = relu(H_s @ w2 + b2); lane holds cat[s*64+lane]
    {
        const float bb = b2[lane];
        float c0 = bb, c1 = bb, c2 = bb;
        #define L2STEP(HA0, HA1, HA2, CC) {                                \
            const float wa = w2[(CC) * 64 + lane];                         \
            c0 = fmaf(HA0, wa, c0);                                        \
            c1 = fmaf(HA1, wa, c1);                                        \
            c2 = fmaf(HA2, wa, c2); }
        #pragma unroll 4
        for (int k4 = 0; k4 < 32; ++k4) {
            const float4 hv0 = *(const float4*)(hbuf +       4 * k4);
            const float4 hv1 = *(const float4*)(hbuf + 128 + 4 * k4);
            const float4 hv2 = *(const float4*)(hbuf + 256 + 4 * k4);
            L2STEP(hv0.x, hv1.x, hv2.x, 4 * k4 + 0)
            L2STEP(hv0.y, hv1.y, hv2.y, 4 * k4 + 1)
            L2STEP(hv0.z, hv1.z, hv2.z, 4 * k4 + 2)
            L2STEP(hv0.w, hv1.w, hv2.w, 4 * k4 + 3)
        }
        #undef L2STEP
        cbuf[lane]       = fmaxf(c0, 0.f);
        cbuf[64 + lane]  = fmaxf(c1, 0.f);
        cbuf[128 + lane] = fmaxf(c2, 0.f);
    }

    // L3: F = relu(cat @ p1[0:192,:] + f1pre); lane holds {lane, lane+64}
    {
        float flo = f1pre[lane], fhi = f1pre[64 + lane];
        #define L3STEP(CA, QQ) {                                           \
            const float wlo = p1[(QQ) * 128 + lane];                       \
            const float whi = p1[(QQ) * 128 + 64 + lane];                  \
            flo = fmaf(CA, wlo, flo); fhi = fmaf(CA, whi, fhi); }
        #pragma unroll 4
        for (int q4 = 0; q4 < 48; ++q4) {
            const float4 cv = *(const float4*)(cbuf + 4 * q4);
            L3STEP(cv.x, 4 * q4 + 0)
            L3STEP(cv.y, 4 * q4 + 1)
            L3STEP(cv.z, 4 * q4 + 2)
            L3STEP(cv.w, 4 * q4 + 3)
        }
        #undef L3STEP
        fbuf[lane]      = fmaxf(flo, 0.f);
        fbuf[64 + lane] = fmaxf(fhi, 0.f);
    }

    // L4: out = relu(F @ p2 + pb2); lane holds out[lane]
    {
        float o = pb2[lane];
        #define L4STEP(FA, JJ) o = fmaf(FA, p2[(JJ) * 64 + lane], o);
        #pragma unroll 4
        for (int j4 = 0; j4 < 32; ++j4) {
            const float4 fv = *(const float4*)(fbuf + 4 * j4);
            L4STEP(fv.x, 4 * j4 + 0)
            L4STEP(fv.y, 4 * j4 + 1)
            L4STEP(fv.z, 4 * j4 + 2)
            L4STEP(fv.w, 4 * j4 + 3)
        }
        #undef L4STEP
        out[n * 64 + lane] = fmaxf(o, 0.f);
    }
}

extern "C" void kernel_launch(void* const* d_in, const int* in_sizes, int n_in,
                              void* d_out, int out_size, void* d_ws, size_t ws_size,
                              hipStream_t stream)
{
    const float* fm    = (const float*)d_in[0];
    const float* boxes = (const float*)d_in[1];
    const float* w1    = (const float*)d_in[2];
    const float* b1    = (const float*)d_in[3];
    const float* w2    = (const float*)d_in[4];
    const float* b2    = (const float*)d_in[5];
    const float* p1    = (const float*)d_in[6];
    const float* pb1   = (const float*)d_in[7];
    const float* p2    = (const float*)d_in[8];
    const float* pb2   = (const float*)d_in[9];
    float* out = (float*)d_out;

    const int N = in_sizes[1] / 4;       // 4096

    float* ws      = (float*)d_ws;
    float* fm_t    = ws;                         // 921600 floats
    float* partial = fm_t + 921600;              // 14400
    float* f1pre   = partial + 14400;            // 128

    k_transpose_mean<<<NPIX / 64, 256, 0, stream>>>(fm, fm_t, partial);
    k_ghead<<<1, 256, 0, stream>>>(partial, w1, b1, w2, b2, p1, pb1, f1pre);
    k_fused<<<(N + 3) / 4, 256, 0, stream>>>(fm_t, boxes, w1, b1, w2, b2,
                                             p1, f1pre, p2, pb2, out, N);
}

// Round 7
// 157.008 us; speedup vs baseline: 1.0011x; 1.0011x over previous
//
#include <hip/hip_runtime.h>
#include <hip/hip_bf16.h>

// EfficientMultiScaleROIExtractor for MI355X (gfx950)
// fm: [1,64,120,120] f32, boxes: [4096,4] f32, MLP weights f32.
//
// K1 k_transpose_mean: CHW->HWC + per-block channel partial sums
// K2 k_ghead: global mean -> shared head -> folded f1 bias (f1pre[128])
// K3 k_fused: 512 threads = 8 waves per block, 4 boxes per block.
//   Pool: 2 waves per box (8 point-groups of 16 lanes); each group
//     recomputes its grid point inline and fetches 4 corners as
//     16-lane float4 (=256B/point/corner, 1KB per VMEM instr).
//     Wave-internal shfl reduce, cross-wave sum via LDS.
//   MLP: block-wide phase parallelism — all 512 threads own outputs in
//     every layer; activations broadcast from LDS (uniform per wave),
//     weights 256B-coalesced and shared across a thread's outputs.
//   8192 waves total -> 32 waves/CU (vs 16 before) for latency hiding.

#define HW 120
#define NPIX (HW * HW)   // 14400

__global__ __launch_bounds__(256) void k_transpose_mean(
    const float* __restrict__ fm, float* __restrict__ fm_t,
    float* __restrict__ partial)
{
    __shared__ float tile[64][65];
    __shared__ float pr[4][64];
    const int t  = threadIdx.x;
    const int tx = t & 63;
    const int ty = t >> 6;
    const int pix0 = blockIdx.x * 64;   // 225 blocks * 64 pixels = 14400

    #pragma unroll
    for (int k = 0; k < 16; ++k) {
        const int c = k * 4 + ty;
        tile[c][tx] = fm[c * NPIX + pix0 + tx];   // coalesced read
    }
    __syncthreads();
    #pragma unroll
    for (int k = 0; k < 16; ++k) {
        const int p = k * 4 + ty;
        fm_t[(pix0 + p) * 64 + tx] = tile[tx][p]; // coalesced write
    }
    float s = 0.f;
    #pragma unroll
    for (int k = 0; k < 16; ++k) s += tile[tx][ty * 16 + k];
    pr[ty][tx] = s;
    __syncthreads();
    if (t < 64)
        partial[blockIdx.x * 64 + t] = pr[0][t] + pr[1][t] + pr[2][t] + pr[3][t];
}

__global__ __launch_bounds__(256) void k_ghead(
    const float* __restrict__ partial,
    const float* __restrict__ w1, const float* __restrict__ b1,
    const float* __restrict__ w2, const float* __restrict__ b2,
    const float* __restrict__ p1, const float* __restrict__ pb1,
    float* __restrict__ f1pre)
{
    __shared__ float pr[4][64];
    __shared__ float g[64];
    __shared__ float h[128];
    __shared__ float gh[64];
    const int t = threadIdx.x;
    const int c = t & 63, q = t >> 6;
    float s = 0.f;
    for (int b = q; b < 225; b += 4) s += partial[b * 64 + c];
    pr[q][c] = s;
    __syncthreads();
    if (t < 64) g[t] = (pr[0][t] + pr[1][t] + pr[2][t] + pr[3][t]) * (1.f / 14400.f);
    __syncthreads();
    if (t < 128) {
        float a = b1[t];
        #pragma unroll 8
        for (int cc = 0; cc < 64; ++cc) a = fmaf(g[cc], w1[cc * 128 + t], a);
        h[t] = fmaxf(a, 0.f);
    }
    __syncthreads();
    if (t < 64) {
        float a = b2[t];
        #pragma unroll 8
        for (int k = 0; k < 128; ++k) a = fmaf(h[k], w2[k * 64 + t], a);
        gh[t] = fmaxf(a, 0.f);
    }
    __syncthreads();
    if (t < 128) {
        float a = pb1[t];
        #pragma unroll 8
        for (int j = 0; j < 64; ++j) a = fmaf(gh[j], p1[(192 + j) * 128 + t], a);
        f1pre[t] = a;   // no relu: relu happens after cat@p1 contribution
    }
}

// One scale's gather with 8 point-groups (2 waves per box). Each 16-lane
// group walks lp = g8, g8+8, ... recomputing the point's bilinear setup
// inline (lockstep within the group). Returns wave-partial sum (over the
// wave's 4 groups) valid in pg==0 lanes after the shfl reduce.
template <int R>
__device__ __forceinline__ float4 gather8(
    const char* __restrict__ fb, int g8,
    float cx, float cy, float bw2, float bh2)
{
    constexpr float invR = 1.f / (float)R;
    constexpr float s2   = invR * invR;          // folds the mean
    float ax = 0.f, ay = 0.f, az = 0.f, aw = 0.f;
    #pragma unroll 2
    for (int lp = g8; lp < R * R; lp += 8) {
        const int i = lp / R;                    // constexpr R -> magic mul
        const int j = lp - i * R;
        const float liny = (float)(2 * i + 1) * invR - 1.f;
        const float linx = (float)(2 * j + 1) * invR - 1.f;
        const float gy = cy + bh2 * liny;
        const float gx = cx + bw2 * linx;
        const float iy = ((gy + 1.f) * 120.f - 1.f) * 0.5f;
        const float ix = ((gx + 1.f) * 120.f - 1.f) * 0.5f;
        const float y0f = floorf(iy), x0f = floorf(ix);
        const float wy = iy - y0f,  wx = ix - x0f;
        const int y0 = (int)y0f, x0 = (int)x0f;
        const float vy0 = (y0 >= 0 && y0 < HW)      ? 1.f : 0.f;
        const float vy1 = (y0 >= -1 && y0 < HW - 1) ? 1.f : 0.f;
        const float vx0 = (x0 >= 0 && x0 < HW)      ? 1.f : 0.f;
        const float vx1 = (x0 >= -1 && x0 < HW - 1) ? 1.f : 0.f;
        const int x0c = min(max(x0, 0), HW - 1);
        const int x1c = min(max(x0 + 1, 0), HW - 1);
        const int y0c = min(max(y0, 0), HW - 1);
        const int y1c = min(max(y0 + 1, 0), HW - 1);
        const int o00 = (y0c * HW + x0c) * 256;  // one HWC pixel = 256B
        const int o01 = (y0c * HW + x1c) * 256;
        const int o10 = (y1c * HW + x0c) * 256;
        const int o11 = (y1c * HW + x1c) * 256;
        const float w00 = (1.f - wx) * (1.f - wy) * s2 * (vy0 * vx0);
        const float w01 = wx * (1.f - wy) * s2 * (vy0 * vx1);
        const float w10 = (1.f - wx) * wy * s2 * (vy1 * vx0);
        const float w11 = wx * wy * s2 * (vy1 * vx1);
        const float4 v0 = *(const float4*)(fb + o00);
        const float4 v1 = *(const float4*)(fb + o01);
        const float4 v2 = *(const float4*)(fb + o10);
        const float4 v3 = *(const float4*)(fb + o11);
        ax = fmaf(w00, v0.x, ax); ay = fmaf(w00, v0.y, ay);
        az = fmaf(w00, v0.z, az); aw = fmaf(w00, v0.w, aw);
        ax = fmaf(w01, v1.x, ax); ay = fmaf(w01, v1.y, ay);
        az = fmaf(w01, v1.z, az); aw = fmaf(w01, v1.w, aw);
        ax = fmaf(w10, v2.x, ax); ay = fmaf(w10, v2.y, ay);
        az = fmaf(w10, v2.z, az); aw = fmaf(w10, v2.w, aw);
        ax = fmaf(w11, v3.x, ax); ay = fmaf(w11, v3.y, ay);
        az = fmaf(w11, v3.z, az); aw = fmaf(w11, v3.w, aw);
    }
    // combine this wave's 4 point-groups (lanes l, l^16, l^32, l^48)
    ax += __shfl_xor(ax, 16, 64); ay += __shfl_xor(ay, 16, 64);
    az += __shfl_xor(az, 16, 64); aw += __shfl_xor(aw, 16, 64);
    ax += __shfl_xor(ax, 32, 64); ay += __shfl_xor(ay, 32, 64);
    az += __shfl_xor(az, 32, 64); aw += __shfl_xor(aw, 32, 64);
    return make_float4(ax, ay, az, aw);
}

__global__ __launch_bounds__(512, 8) void k_fused(
    const float* __restrict__ fm_t, const float* __restrict__ boxes,
    const float* __restrict__ w1, const float* __restrict__ b1,
    const float* __restrict__ w2, const float* __restrict__ b2,
    const float* __restrict__ p1, const float* __restrict__ f1pre,
    const float* __restrict__ p2, const float* __restrict__ pb2,
    float* __restrict__ out, int N)
{
    __shared__ __align__(16) float xpart[4][2][192]; // per-box per-half pooled partials
    __shared__ __align__(16) float xbuf[4][192];     // pooled [3][64] per box
    __shared__ __align__(16) float hbuf[4][384];     // H [3][128] per box
    __shared__ __align__(16) float cbuf[4][192];     // cat per box
    __shared__ __align__(16) float fbuf[4][128];     // F per box
    __shared__ __align__(16) float opart[2][4][64];  // L4 split-K partials

    const int t    = threadIdx.x;
    const int lane = t & 63;
    const int w    = t >> 6;        // wave 0..7
    const int n0   = blockIdx.x * 4;

    // ---------------- pool: 2 waves per box ----------------
    {
        const int b  = w >> 1;      // box slot 0..3
        const int hf = w & 1;       // which half of the points
        const int qc = lane & 15;   // channel quad
        const int pg = lane >> 4;   // point group within wave
        const int g8 = hf * 4 + pg; // global point group 0..7
        const int n  = n0 + b;

        if (n < N) {
            const float4 bx = reinterpret_cast<const float4*>(boxes)[n];
            const float x1 = bx.x / 960.f * 2.f - 1.f;
            const float y1 = bx.y / 960.f * 2.f - 1.f;
            const float x2 = bx.z / 960.f * 2.f - 1.f;
            const float y2 = bx.w / 960.f * 2.f - 1.f;
            const float cx  = (x1 + x2) * 0.5f;
            const float cy  = (y1 + y2) * 0.5f;
            const float bw2 = fmaxf(x2 - x1, 1e-6f) * 0.5f;
            const float bh2 = fmaxf(y2 - y1, 1e-6f) * 0.5f;
            const char* fb = (const char*)fm_t + qc * 16;

            const float4 r0 = gather8<3>(fb, g8, cx, cy, bw2, bh2);
            if (pg == 0) *(float4*)(&xpart[b][hf][4 * qc]) = r0;
            const float4 r1 = gather8<7>(fb, g8, cx, cy, bw2, bh2);
            if (pg == 0) *(float4*)(&xpart[b][hf][64 + 4 * qc]) = r1;
            const float4 r2 = gather8<11>(fb, g8, cx, cy, bw2, bh2);
            if (pg == 0) *(float4*)(&xpart[b][hf][128 + 4 * qc]) = r2;
        } else if (pg == 0) {
            const float4 z = make_float4(0.f, 0.f, 0.f, 0.f);
            *(float4*)(&xpart[b][hf][4 * qc]) = z;
            *(float4*)(&xpart[b][hf][64 + 4 * qc]) = z;
            *(float4*)(&xpart[b][hf][128 + 4 * qc]) = z;
        }
    }
    __syncthreads();

    // sum the two halves: 768 values
    {
        int i = t;
        { const int b = i / 192, r = i - b * 192;
          xbuf[b][r] = xpart[b][0][r] + xpart[b][1][r]; }
        if (t < 256) {
            i = 512 + t;
            const int b = i / 192, r = i - b * 192;
            xbuf[b][r] = xpart[b][0][r] + xpart[b][1][r];
        }
    }
    __syncthreads();

    // ---------------- L1: 4 boxes x 3 scales x 128 outs = 1536 = 3 per thread ----
    {
        const int k  = t & 127;          // output column (fixed across reps)
        const int wp = t >> 7;           // wave-pair 0..3
        // rep r handles group G = r*4 + wp -> (box = G/3, scale = G%3)
        int b0, s0, b1_, s1_, b2_, s2_;
        { const int G = wp;      b0 = G / 3;  s0 = G - 3 * b0; }
        { const int G = 4 + wp;  b1_ = G / 3; s1_ = G - 3 * b1_; }
        { const int G = 8 + wp;  b2_ = G / 3; s2_ = G - 3 * b2_; }
        const float* xb0 = xbuf[b0] + s0 * 64;
        const float* xb1 = xbuf[b1_] + s1_ * 64;
        const float* xb2 = xbuf[b2_] + s2_ * 64;
        const float bias = b1[k];
        float a0 = bias, a1 = bias, a2 = bias;
        #pragma unroll 4
        for (int c4 = 0; c4 < 16; ++c4) {
            const float4 xv0 = *(const float4*)(xb0 + 4 * c4);  // uniform -> bcast
            const float4 xv1 = *(const float4*)(xb1 + 4 * c4);
            const float4 xv2 = *(const float4*)(xb2 + 4 * c4);
            #define W1LD(CI) w1[(4 * c4 + CI) * 128 + k]
            { const float wv = W1LD(0);
              a0 = fmaf(xv0.x, wv, a0); a1 = fmaf(xv1.x, wv, a1); a2 = fmaf(xv2.x, wv, a2); }
            { const float wv = W1LD(1);
              a0 = fmaf(xv0.y, wv, a0); a1 = fmaf(xv1.y, wv, a1); a2 = fmaf(xv2.y, wv, a2); }
            { const float wv = W1LD(2);
              a0 = fmaf(xv0.z, wv, a0); a1 = fmaf(xv1.z, wv, a1); a2 = fmaf(xv2.z, wv, a2); }
            { const float wv = W1LD(3);
              a0 = fmaf(xv0.w, wv, a0); a1 = fmaf(xv1.w, wv, a1); a2 = fmaf(xv2.w, wv, a2); }
            #undef W1LD
        }
        hbuf[b0][s0 * 128 + k]  = fmaxf(a0, 0.f);
        hbuf[b1_][s1_ * 128 + k] = fmaxf(a1, 0.f);
        hbuf[b2_][s2_ * 128 + k] = fmaxf(a2, 0.f);
    }
    __syncthreads();

    // ---------------- L2: 4 boxes x 3 scales x 64 outs = 768 ----------------
    {
        const int co = lane;             // output column
        // rep0: G = w (all); rep1: G = 8 + w (only waves 0..3)
        const int G0 = w;
        const int b0 = G0 / 3, s0 = G0 - 3 * b0;
        const float* hb0 = hbuf[b0] + s0 * 128;
        const bool two = (w < 4);
        const int G1 = 8 + w;
        const int b1_ = two ? (G1 / 3) : 0, s1_ = two ? (G1 - 3 * (G1 / 3)) : 0;
        const float* hb1 = hbuf[b1_] + s1_ * 128;
        const float bias = b2[co];
        float a0 = bias, a1 = bias;
        #pragma unroll 4
        for (int c4 = 0; c4 < 32; ++c4) {
            const float4 hv0 = *(const float4*)(hb0 + 4 * c4);
            const float4 hv1 = *(const float4*)(hb1 + 4 * c4);
            #define W2LD(CI) w2[(4 * c4 + CI) * 64 + co]
            { const float wv = W2LD(0); a0 = fmaf(hv0.x, wv, a0); a1 = fmaf(hv1.x, wv, a1); }
            { const float wv = W2LD(1); a0 = fmaf(hv0.y, wv, a0); a1 = fmaf(hv1.y, wv, a1); }
            { const float wv = W2LD(2); a0 = fmaf(hv0.z, wv, a0); a1 = fmaf(hv1.z, wv, a1); }
            { const float wv = W2LD(3); a0 = fmaf(hv0.w, wv, a0); a1 = fmaf(hv1.w, wv, a1); }
            #undef W2LD
        }
        cbuf[b0][s0 * 64 + co] = fmaxf(a0, 0.f);
        if (two) cbuf[b1_][s1_ * 64 + co] = fmaxf(a1, 0.f);
    }
    __syncthreads();

    // ---------------- L3: 4 boxes x 128 outs = 512 = 1 per thread ----------------
    {
        const int k = t & 127;
        const int b = t >> 7;
        const float* cb = cbuf[b];
        float a = f1pre[k];              // includes pb1 + global-branch term
        #pragma unroll 4
        for (int q4 = 0; q4 < 48; ++q4) {
            const float4 cv = *(const float4*)(cb + 4 * q4);
            a = fmaf(cv.x, p1[(4 * q4 + 0) * 128 + k], a);
            a = fmaf(cv.y, p1[(4 * q4 + 1) * 128 + k], a);
            a = fmaf(cv.z, p1[(4 * q4 + 2) * 128 + k], a);
            a = fmaf(cv.w, p1[(4 * q4 + 3) * 128 + k], a);
        }
        fbuf[b][k] = fmaxf(a, 0.f);
    }
    __syncthreads();

    // ---------------- L4: 4 boxes x 64 outs, K=128 split across 2 thread-halves ---
    {
        const int kh = t >> 8;           // 0 or 1 (uniform per wave)
        const int b  = (t >> 6) & 3;     // box (uniform per wave)
        const int co = lane;
        const float* fbp = fbuf[b] + kh * 64;
        float a = kh ? 0.f : pb2[co];
        #pragma unroll 4
        for (int j4 = 0; j4 < 16; ++j4) {
            const float4 fv = *(const float4*)(fbp + 4 * j4);
            a = fmaf(fv.x, p2[(kh * 64 + 4 * j4 + 0) * 64 + co], a);
            a = fmaf(fv.y, p2[(kh * 64 + 4 * j4 + 1) * 64 + co], a);
            a = fmaf(fv.z, p2[(kh * 64 + 4 * j4 + 2) * 64 + co], a);
            a = fmaf(fv.w, p2[(kh * 64 + 4 * j4 + 3) * 64 + co], a);
        }
        opart[kh][b][co] = a;
    }
    __syncthreads();
    if (t < 256) {
        const int b  = t >> 6;
        const int co = lane;
        const int n  = n0 + b;
        if (n < N)
            out[n * 64 + co] = fmaxf(opart[0][b][co] + opart[1][b][co], 0.f);
    }
}

extern "C" void kernel_launch(void* const* d_in, const int* in_sizes, int n_in,
                              void* d_out, int out_size, void* d_ws, size_t ws_size,
                              hipStream_t stream)
{
    const float* fm    = (const float*)d_in[0];
    const float* boxes = (const float*)d_in[1];
    const float* w1    = (const float*)d_in[2];
    const float* b1    = (const float*)d_in[3];
    const float* w2    = (const float*)d_in[4];
    const float* b2    = (const float*)d_in[5];
    const float* p1    = (const float*)d_in[6];
    const float* pb1   = (const float*)d_in[7];
    const float* p2    = (const float*)d_in[8];
    const float* pb2   = (const float*)d_in[9];
    float* out = (float*)d_out;

    const int N = in_sizes[1] / 4;       // 4096

    float* ws      = (float*)d_ws;
    float* fm_t    = ws;                         // 921600 floats
    float* partial = fm_t + 921600;              // 14400
    float* f1pre   = partial + 14400;            // 128

    k_transpose_mean<<<NPIX / 64, 256, 0, stream>>>(fm, fm_t, partial);
    k_ghead<<<1, 256, 0, stream>>>(partial, w1, b1, w2, b2, p1, pb1, f1pre);
    k_fused<<<(N + 3) / 4, 512, 0, stream>>>(fm_t, boxes, w1, b1, w2, b2,
                                             p1, f1pre, p2, pb2, out, N);
}